// Round 2
// baseline (8912.959 us; speedup 1.0000x reference)
//
#include <hip/hip_runtime.h>

typedef short short8 __attribute__((ext_vector_type(8)));
typedef float f32x4  __attribute__((ext_vector_type(4)));

#define SCOPE_AGENT __HIP_MEMORY_SCOPE_AGENT

__device__ __forceinline__ ushort f2bf(float f){
  unsigned u = __float_as_uint(f);
  u = (u + 0x7FFFu + ((u >> 16) & 1u)) >> 16;
  return (ushort)u;
}
__device__ __forceinline__ float bf2f(ushort h){
  return __uint_as_float(((unsigned)h) << 16);
}
__device__ __forceinline__ float wred_sum(float v){
  #pragma unroll
  for (int m = 1; m < 64; m <<= 1) v += __shfl_xor(v, m, 64);
  return v;
}
__device__ __forceinline__ float wred_max(float v){
  #pragma unroll
  for (int m = 1; m < 64; m <<= 1) v = fmaxf(v, __shfl_xor(v, m, 64));
  return v;
}

// ---------------------------------------------------------------------------
// Generic bf16 MFMA GEMM:  C[M,N] = A[M,K] * W[N,K]^T (+bias) (+act)
// M,N multiples of 64; K multiple of 32. 64x64 block tile, 4 waves (2x2 of 32x32).
// act: 0 = none, 1 = relu^2
// ---------------------------------------------------------------------------
__global__ __launch_bounds__(256) void gemm_bt(
    const ushort* __restrict__ A, const ushort* __restrict__ W,
    const float* __restrict__ bias,
    float* __restrict__ outF, ushort* __restrict__ outB,
    int M, int N, int K, int act)
{
  __shared__ __align__(16) ushort As[64][56];   // 112B row stride: 16B aligned, ~2-way banks
  __shared__ __align__(16) ushort Ws[64][56];
  const int bn = blockIdx.x * 64, bm = blockIdx.y * 64;
  const int tid = threadIdx.x, lane = tid & 63, wave = tid >> 6;
  const int wm = (wave >> 1) * 32, wn = (wave & 1) * 32;
  const int lr = tid >> 2, lc = (tid & 3) * 8;
  const int fr = lane & 15, kg = (lane >> 4) * 8;

  f32x4 acc00 = {0.f,0.f,0.f,0.f}, acc01 = {0.f,0.f,0.f,0.f};
  f32x4 acc10 = {0.f,0.f,0.f,0.f}, acc11 = {0.f,0.f,0.f,0.f};

  const size_t arow = (size_t)(bm + lr) * K;
  const size_t wrow = (size_t)(bn + lr) * K;

  for (int k0 = 0; k0 < K; k0 += 32){
    *(uint4*)&As[lr][lc] = *(const uint4*)&A[arow + k0 + lc];
    *(uint4*)&Ws[lr][lc] = *(const uint4*)&W[wrow + k0 + lc];
    __syncthreads();
    short8 a0 = *(const short8*)&As[wm + fr][kg];
    short8 a1 = *(const short8*)&As[wm + 16 + fr][kg];
    short8 b0 = *(const short8*)&Ws[wn + fr][kg];
    short8 b1 = *(const short8*)&Ws[wn + 16 + fr][kg];
    acc00 = __builtin_amdgcn_mfma_f32_16x16x32_bf16(a0, b0, acc00, 0, 0, 0);
    acc01 = __builtin_amdgcn_mfma_f32_16x16x32_bf16(a0, b1, acc01, 0, 0, 0);
    acc10 = __builtin_amdgcn_mfma_f32_16x16x32_bf16(a1, b0, acc10, 0, 0, 0);
    acc11 = __builtin_amdgcn_mfma_f32_16x16x32_bf16(a1, b1, acc11, 0, 0, 0);
    __syncthreads();
  }

  const int rbase = bm + wm + (lane >> 4) * 4;
  #pragma unroll
  for (int fm = 0; fm < 2; ++fm){
    f32x4 v0 = fm ? acc10 : acc00;
    f32x4 v1 = fm ? acc11 : acc01;
    #pragma unroll
    for (int j = 0; j < 4; ++j){
      const int row = rbase + fm * 16 + j;
      {
        const int col = bn + wn + fr;
        float v = v0[j] + (bias ? bias[col] : 0.f);
        if (act == 1){ v = fmaxf(v, 0.f); v = v * v; }
        if (outF) outF[(size_t)row * N + col] = v;
        if (outB) outB[(size_t)row * N + col] = f2bf(v);
      }
      {
        const int col = bn + wn + 16 + fr;
        float v = v1[j] + (bias ? bias[col] : 0.f);
        if (act == 1){ v = fmaxf(v, 0.f); v = v * v; }
        if (outF) outF[(size_t)row * N + col] = v;
        if (outB) outB[(size_t)row * N + col] = f2bf(v);
      }
    }
  }
}

// ---------------------------------------------------------------------------
// Persistent dataflow GRU. 128 blocks x 256 threads. Each wave owns 2 hidden
// units; w_hh rows live in VGPRs. Step hand-off via write-once 0xFFFFFFFF
// sentinel words in hcomm (h in (-1,1) so the -NaN pattern is impossible).
// hcomm layout: [t][b][1024] u32.  states: [b][t][1024] f32.
// ---------------------------------------------------------------------------
__global__ __launch_bounds__(256, 1) void gru_kernel(
    const float* __restrict__ xp,   // [b][t][3072] (includes b_ih)
    const float* __restrict__ whh,  // [3072][1024]
    const float* __restrict__ bhh,  // [3072]
    float* __restrict__ states,     // [b][t][1024]
    unsigned* __restrict__ hcomm)   // [1024][2][1024]
{
  const int wave = threadIdx.x >> 6, lane = threadIdx.x & 63;
  const int U0 = blockIdx.x * 8 + wave * 2;

  float wrf[2][3][16];
  float bh[2][3];
  #pragma unroll
  for (int u = 0; u < 2; ++u){
    #pragma unroll
    for (int g = 0; g < 3; ++g){
      const int row = g * 1024 + U0 + u;
      const float4* src = (const float4*)(whh + (size_t)row * 1024);
      #pragma unroll
      for (int i = 0; i < 4; ++i){
        float4 v = src[i * 64 + lane];
        wrf[u][g][i*4+0] = v.x; wrf[u][g][i*4+1] = v.y;
        wrf[u][g][i*4+2] = v.z; wrf[u][g][i*4+3] = v.w;
      }
      bh[u][g] = bhh[row];
    }
  }

  for (int t = 0; t < 1024; ++t){
    // prefetch xp for this step (independent of h)
    float xr = 0.f, xz = 0.f, xn = 0.f;
    if (lane < 4){
      const int b = lane & 1, u = lane >> 1;
      const size_t xoff = ((size_t)(b * 1024 + t)) * 3072 + (U0 + u);
      xr = xp[xoff]; xz = xp[xoff + 1024]; xn = xp[xoff + 2048];
    }

    unsigned hu[32];   // [b*16 + ii], k = (ii>>2)*256 + lane*4 + (ii&3)
    if (t > 0){
      unsigned* hb = hcomm + (size_t)(t - 1) * 2048;
      #pragma unroll
      for (int j = 0; j < 32; ++j){
        const int b = j >> 4, ii = j & 15;
        hu[j] = __hip_atomic_load(hb + b * 1024 + (ii >> 2) * 256 + lane * 4 + (ii & 3),
                                  __ATOMIC_RELAXED, SCOPE_AGENT);
      }
      int guard = 0;
      while (1){
        int pend = 0;
        #pragma unroll
        for (int j = 0; j < 32; ++j) pend |= (hu[j] == 0xFFFFFFFFu) ? 1 : 0;
        if (!__any(pend)) break;
        if (++guard > (1 << 18)){
          // fail-safe: never hang; sanitize leftover sentinels to 0.0f so the
          // run finishes with a finite (wrong) answer instead of NaN poison
          #pragma unroll
          for (int j = 0; j < 32; ++j) if (hu[j] == 0xFFFFFFFFu) hu[j] = 0u;
          break;
        }
        __builtin_amdgcn_s_sleep(1);
        #pragma unroll
        for (int j = 0; j < 32; ++j){
          if (hu[j] == 0xFFFFFFFFu){
            const int b = j >> 4, ii = j & 15;
            hu[j] = __hip_atomic_load(hb + b * 1024 + (ii >> 2) * 256 + lane * 4 + (ii & 3),
                                      __ATOMIC_RELAXED, SCOPE_AGENT);
          }
        }
      }
    } else {
      #pragma unroll
      for (int j = 0; j < 32; ++j) hu[j] = 0u;   // h0 = 0.0f
    }

    float p2[2][2][3];
    #pragma unroll
    for (int b = 0; b < 2; ++b)
      #pragma unroll
      for (int u = 0; u < 2; ++u)
        #pragma unroll
        for (int g = 0; g < 3; ++g) p2[b][u][g] = 0.f;

    #pragma unroll
    for (int ii = 0; ii < 16; ++ii){
      const float h0 = __uint_as_float(hu[ii]);
      const float h1 = __uint_as_float(hu[16 + ii]);
      #pragma unroll
      for (int u = 0; u < 2; ++u)
        #pragma unroll
        for (int g = 0; g < 3; ++g){
          const float wv = wrf[u][g][ii];
          p2[0][u][g] = fmaf(h0, wv, p2[0][u][g]);
          p2[1][u][g] = fmaf(h1, wv, p2[1][u][g]);
        }
    }
    #pragma unroll
    for (int b = 0; b < 2; ++b)
      #pragma unroll
      for (int u = 0; u < 2; ++u)
        #pragma unroll
        for (int g = 0; g < 3; ++g) p2[b][u][g] = wred_sum(p2[b][u][g]);

    if (lane < 4){
      const int b = lane & 1, u = lane >> 1, U = U0 + u;
      float dr = 0.f, dz = 0.f, dn = 0.f;
      #pragma unroll
      for (int uu = 0; uu < 2; ++uu)
        #pragma unroll
        for (int bb = 0; bb < 2; ++bb){
          const bool sel = (lane == (uu * 2 + bb));
          dr = sel ? (p2[bb][uu][0] + bh[uu][0]) : dr;
          dz = sel ? (p2[bb][uu][1] + bh[uu][1]) : dz;
          dn = sel ? (p2[bb][uu][2] + bh[uu][2]) : dn;
        }
      const float rg = 1.f / (1.f + __expf(-(xr + dr)));
      const float zg = 1.f / (1.f + __expf(-(xz + dz)));
      const float ng = tanhf(xn + rg * dn);
      float hp = 0.f;
      if (t > 0){
        unsigned hpu = __hip_atomic_load(hcomm + (size_t)(t - 1) * 2048 + b * 1024 + U,
                                         __ATOMIC_RELAXED, SCOPE_AGENT);
        if (hpu == 0xFFFFFFFFu) hpu = 0u;   // sanitize (only possible after guard expiry)
        hp = __uint_as_float(hpu);
      }
      const float hnew = (1.f - zg) * ng + zg * hp;
      states[((size_t)(b * 1024 + t)) * 1024 + U] = hnew;
      __hip_atomic_store(hcomm + (size_t)t * 2048 + b * 1024 + U, __float_as_uint(hnew),
                         __ATOMIC_RELAXED, SCOPE_AGENT);
    }
  }
}

// ---------------------------------------------------------------------------
// Small helper kernels
// ---------------------------------------------------------------------------
__global__ void fill_u32(unsigned* __restrict__ p, unsigned v, int n){
  int i = blockIdx.x * 256 + threadIdx.x;
  if (i < n) p[i] = v;
}

__global__ void f32_to_bf16(const float* __restrict__ s, ushort* __restrict__ d, int n){
  int i = blockIdx.x * 256 + threadIdx.x;
  if (i < n) d[i] = f2bf(s[i]);
}

__global__ void pack_qkvb_kernel(const float* qb, const float* kb, const float* vb, float* dst){
  int i = blockIdx.x * 256 + threadIdx.x;
  if (i < 1024) dst[i] = (i < 256) ? qb[i] : (i < 512) ? kb[i - 256] : vb[i - 512];
}

__global__ void gather_x_kernel(const int* __restrict__ ids, const float* __restrict__ emb,
                                ushort* __restrict__ x){
  int idx = blockIdx.x * 256 + threadIdx.x;    // 2048*512
  int r = idx >> 9, e = idx & 511;
  x[idx] = f2bf(emb[(size_t)ids[r] * 512 + e]);
}

__global__ void summary_kernel(const float* __restrict__ states, float* __restrict__ summary){
  int b = blockIdx.x >> 4, c = blockIdx.x & 15;
  for (int h = threadIdx.x; h < 1024; h += 256){
    float acc = 0.f;
    for (int t = 0; t < 64; ++t)
      acc += states[(size_t)(b * 1024 + c * 64 + t) * 1024 + h];
    summary[(size_t)(b * 16 + c) * 1024 + h] = acc * (1.f / 64.f);
  }
}

__global__ __launch_bounds__(256) void gkgv_kernel(
    const float* __restrict__ summary, const float* __restrict__ kw, const float* __restrict__ kb,
    const float* __restrict__ vw, const float* __restrict__ vb,
    float* __restrict__ gk, float* __restrict__ gv)
{
  int b = blockIdx.x >> 4, c = blockIdx.x & 15;
  __shared__ float s[1024];
  for (int i = threadIdx.x; i < 1024; i += 256)
    s[i] = summary[(size_t)(b * 16 + c) * 1024 + i];
  __syncthreads();
  for (int o = threadIdx.x; o < 768; o += 256){
    const float* w; float bias;
    if (o < 256){ w = kw + (size_t)o * 1024; bias = kb[o]; }
    else        { w = vw + (size_t)(o - 256) * 1024; bias = vb[o - 256]; }
    float acc = 0.f;
    for (int k = 0; k < 1024; ++k) acc = fmaf(s[k], w[k], acc);
    acc += bias;
    if (o < 256) gk[(size_t)(b * 16 + c) * 256 + o] = acc;
    else         gv[(size_t)(b * 16 + c) * 512 + (o - 256)] = acc;
  }
}

__global__ __launch_bounds__(256) void mix_kernel(
    const float* __restrict__ states, const float* __restrict__ mixw,
    const float* __restrict__ mixb, float* __restrict__ mix)
{
  int wave = threadIdx.x >> 6, lane = threadIdx.x & 63;
  int r = blockIdx.x * 4 + wave;
  const float* sr = states + (size_t)r * 1024;
  float d0 = 0.f, d1 = 0.f;
  #pragma unroll
  for (int i = 0; i < 16; ++i){
    float sv = sr[lane + 64 * i];
    d0 = fmaf(sv, mixw[lane + 64 * i], d0);
    d1 = fmaf(sv, mixw[1024 + lane + 64 * i], d1);
  }
  d0 = wred_sum(d0); d1 = wred_sum(d1);
  if (lane == 0){
    d0 += mixb[0]; d1 += mixb[1];
    float m = fmaxf(d0, d1);
    float e0 = __expf(d0 - m), e1 = __expf(d1 - m);
    float inv = 1.f / (e0 + e1);
    mix[r * 2] = e0 * inv; mix[r * 2 + 1] = e1 * inv;
  }
}

// qkv layout: [r][0..255]=q, [256..511]=k, [512..1023]=v (bf16)
__global__ __launch_bounds__(256) void local_attn_kernel(
    const ushort* __restrict__ qkv, ushort* __restrict__ lctx)
{
  const int qi = blockIdx.x, b = blockIdx.y;
  const int r = b * 1024 + qi;
  const int nk = min(qi, 128), ks0 = qi - nk;
  __shared__ float qf[256];
  __shared__ float sc[128];
  __shared__ float ps[128];
  const int tid = threadIdx.x;
  qf[tid] = bf2f(qkv[(size_t)r * 1024 + tid]);
  __syncthreads();
  if (tid < 128){
    float s = -1e30f;
    if (tid < nk){
      const ushort* krow = qkv + (size_t)(b * 1024 + ks0 + tid) * 1024 + 256;
      float acc = 0.f;
      for (int m = 0; m < 256; m += 2){
        unsigned u = *(const unsigned*)&krow[m];
        acc = fmaf(qf[m],     bf2f((ushort)(u & 0xFFFFu)), acc);
        acc = fmaf(qf[m + 1], bf2f((ushort)(u >> 16)),     acc);
      }
      s = acc * (1.f / 16.f);
    }
    sc[tid] = s;
  }
  __syncthreads();
  if (tid < 64){
    float s0 = sc[tid], s1 = sc[tid + 64];
    bool v0 = tid < nk, v1 = (tid + 64) < nk;
    float m = fmaxf(v0 ? s0 : -1e30f, v1 ? s1 : -1e30f);
    m = wred_max(m);
    float e0 = v0 ? __expf(s0 - m) : 0.f;
    float e1 = v1 ? __expf(s1 - m) : 0.f;
    float sum = wred_sum(e0 + e1);
    float inv = sum > 0.f ? 1.f / sum : 0.f;
    ps[tid] = e0 * inv; ps[tid + 64] = e1 * inv;
  }
  __syncthreads();
  float a0 = 0.f, a1 = 0.f;
  for (int j = 0; j < nk; ++j){
    float pj = ps[j];
    const ushort* vrow = qkv + (size_t)(b * 1024 + ks0 + j) * 1024 + 512;
    a0 = fmaf(pj, bf2f(vrow[tid]), a0);
    a1 = fmaf(pj, bf2f(vrow[tid + 256]), a1);
  }
  lctx[(size_t)r * 512 + tid] = f2bf(a0);
  lctx[(size_t)r * 512 + tid + 256] = f2bf(a1);
}

__global__ __launch_bounds__(256) void global_attn_kernel(
    const ushort* __restrict__ qkv, const float* __restrict__ gk,
    const float* __restrict__ gv, ushort* __restrict__ gctx)
{
  const int wave = threadIdx.x >> 6, lane = threadIdx.x & 63;
  const int qi = blockIdx.x * 4 + wave, b = blockIdx.y;
  const int r = b * 1024 + qi;
  float q4[4];
  {
    const ushort* qp = qkv + (size_t)r * 1024 + lane * 4;
    unsigned u0 = *(const unsigned*)&qp[0];
    unsigned u1 = *(const unsigned*)&qp[2];
    q4[0] = bf2f((ushort)(u0 & 0xFFFFu)); q4[1] = bf2f((ushort)(u0 >> 16));
    q4[2] = bf2f((ushort)(u1 & 0xFFFFu)); q4[3] = bf2f((ushort)(u1 >> 16));
  }
  float p[16];
  float mx = -1e30f;
  #pragma unroll
  for (int c = 0; c < 16; ++c){
    const float* gkr = gk + ((size_t)(b * 16 + c)) * 256 + lane * 4;
    float acc = q4[0]*gkr[0] + q4[1]*gkr[1] + q4[2]*gkr[2] + q4[3]*gkr[3];
    acc = wred_sum(acc);
    const bool valid = (c * 64 + 63) < (qi - 128);
    p[c] = valid ? acc * (1.f / 16.f) : -1e30f;
    if (valid) mx = fmaxf(mx, p[c]);
  }
  float sum = 0.f;
  #pragma unroll
  for (int c = 0; c < 16; ++c){
    const bool valid = (c * 64 + 63) < (qi - 128);
    float e = valid ? __expf(p[c] - mx) : 0.f;
    p[c] = e; sum += e;
  }
  const float inv = sum > 0.f ? 1.f / sum : 0.f;
  #pragma unroll
  for (int c = 0; c < 16; ++c) p[c] *= inv;
  #pragma unroll
  for (int i = 0; i < 8; ++i){
    float acc = 0.f;
    #pragma unroll
    for (int c = 0; c < 16; ++c)
      acc = fmaf(p[c], gv[((size_t)(b * 16 + c)) * 512 + i * 64 + lane], acc);
    gctx[(size_t)r * 512 + i * 64 + lane] = f2bf(acc);
  }
}

__global__ void fused_feat_kernel(
    const ushort* __restrict__ bfeat, const ushort* __restrict__ lc,
    const ushort* __restrict__ gc, const float* __restrict__ mix,
    const float* __restrict__ lsp, const float* __restrict__ gsp,
    ushort* __restrict__ outp)
{
  int idx = blockIdx.x * 256 + threadIdx.x;   // 2048*512
  int r = idx >> 9;
  float v = bf2f(bfeat[idx])
          + mix[r * 2]     * lsp[0] * bf2f(lc[idx])
          + mix[r * 2 + 1] * gsp[0] * bf2f(gc[idx]);
  outp[idx] = f2bf(v);
}

__global__ void scatter_add_kernel(const float* __restrict__ tp, const int* __restrict__ ids,
                                   float* __restrict__ out){
  int idx = blockIdx.x * 256 + threadIdx.x;   // 2048*4096
  int r = idx >> 12, pcol = idx & 4095;
  atomicAdd(&out[(size_t)r * 32000 + ids[pcol]], tp[idx]);
}

// ---------------------------------------------------------------------------
extern "C" void kernel_launch(void* const* d_in, const int* in_sizes, int n_in,
                              void* d_out, int out_size, void* d_ws, size_t ws_size,
                              hipStream_t stream)
{
  const int*   ids    = (const int*)  d_in[0];
  const int*   untied = (const int*)  d_in[1];
  const float* emb    = (const float*)d_in[2];
  const float* gwih   = (const float*)d_in[3];
  const float* gwhh   = (const float*)d_in[4];
  const float* gbih   = (const float*)d_in[5];
  const float* gbhh   = (const float*)d_in[6];
  const float* fcw    = (const float*)d_in[7];
  const float* fcb    = (const float*)d_in[8];
  const float* projw  = (const float*)d_in[9];
  const float* projb  = (const float*)d_in[10];
  const float* outbia = (const float*)d_in[11];
  const float* partw  = (const float*)d_in[12];
  const float* partb  = (const float*)d_in[13];
  const float* qw     = (const float*)d_in[14];
  const float* qb     = (const float*)d_in[15];
  const float* kw     = (const float*)d_in[16];
  const float* kb     = (const float*)d_in[17];
  const float* vw     = (const float*)d_in[18];
  const float* vb     = (const float*)d_in[19];
  const float* mixw   = (const float*)d_in[20];
  const float* mixb   = (const float*)d_in[21];
  const float* lsp    = (const float*)d_in[22];
  const float* gsp    = (const float*)d_in[23];
  float* out = (float*)d_out;

  char* base = (char*)d_ws;
  size_t off = 0;
  auto alloc = [&](size_t b)->char*{
    char* p = base + off; off += (b + 255) & ~(size_t)255; return p;
  };

  float*    regionA  = (float*)   alloc(2048ull * 4096 * 4);  // xp, then total_partial
  float*    xp       = regionA;                               // [2048][3072]
  float*    tpart    = regionA;                               // [2048][4096]
  float*    states   = (float*)   alloc(2048ull * 1024 * 4);
  ushort*   statesbf = (ushort*)  alloc(2048ull * 1024 * 2);
  ushort*   embbf    = (ushort*)  alloc(32000ull * 512 * 2);
  ushort*   xbf      = (ushort*)  alloc(2048ull * 512 * 2);
  ushort*   wihbf    = (ushort*)  alloc(3072ull * 512 * 2);
  ushort*   fcwbf    = (ushort*)  alloc(2048ull * 1024 * 2);
  ushort*   projwbf  = (ushort*)  alloc(512ull * 2048 * 2);
  ushort*   partwbf  = (ushort*)  alloc(4096ull * 512 * 2);
  ushort*   qkvwbf   = (ushort*)  alloc(1024ull * 1024 * 2);
  float*    qkvbias  = (float*)   alloc(1024 * 4);
  unsigned* hcomm    = (unsigned*)alloc(1024ull * 2048 * 4);  // then head_bf
  ushort*   headbf   = (ushort*)  hcomm;                      // [2048][2048]
  ushort*   bfeatbf  = (ushort*)  alloc(2048ull * 512 * 2);
  ushort*   qkvbf    = (ushort*)  alloc(2048ull * 1024 * 2);
  float*    summary  = (float*)   alloc(2ull * 16 * 1024 * 4);
  float*    gkbuf    = (float*)   alloc(2ull * 16 * 256 * 4);
  float*    gvbuf    = (float*)   alloc(2ull * 16 * 512 * 4);
  float*    mix      = (float*)   alloc(2048ull * 2 * 4);
  ushort*   lctx     = (ushort*)  alloc(2048ull * 512 * 2);
  ushort*   gctx     = (ushort*)  alloc(2048ull * 512 * 2);
  ushort*   fusedbf  = (ushort*)  alloc(2048ull * 512 * 2);
  if (off > ws_size) return;   // workspace too small: fail loudly (absmax) not OOB

  auto cv = [&](const float* s, ushort* d, long long n){
    f32_to_bf16<<<dim3((unsigned)((n + 255) / 256)), dim3(256), 0, stream>>>(s, d, (int)n);
  };

  // weight conversion / packing
  cv(emb,   embbf,   32000ll * 512);
  cv(gwih,  wihbf,   3072ll * 512);
  cv(fcw,   fcwbf,   2048ll * 1024);
  cv(projw, projwbf, 512ll * 2048);
  cv(partw, partwbf, 4096ll * 512);
  cv(qw, qkvwbf,               256ll * 1024);
  cv(kw, qkvwbf + 256 * 1024,  256ll * 1024);
  cv(vw, qkvwbf + 512 * 1024,  512ll * 1024);
  pack_qkvb_kernel<<<4, 256, 0, stream>>>(qb, kb, vb, qkvbias);
  fill_u32<<<(1024 * 2048 + 255) / 256, 256, 0, stream>>>(hcomm, 0xFFFFFFFFu, 1024 * 2048);

  // embedding gather + GRU input projection
  gather_x_kernel<<<4096, 256, 0, stream>>>(ids, emb, xbf);
  gemm_bt<<<dim3(3072 / 64, 32), 256, 0, stream>>>(xbf, wihbf, gbih, xp, nullptr,
                                                   2048, 3072, 512, 0);
  // recurrent core
  gru_kernel<<<128, 256, 0, stream>>>(xp, gwhh, gbhh, states, hcomm);
  cv(states, statesbf, 2048ll * 1024);

  // feed-forward head
  gemm_bt<<<dim3(2048 / 64, 32), 256, 0, stream>>>(statesbf, fcwbf, fcb, nullptr, headbf,
                                                   2048, 2048, 1024, 1);
  gemm_bt<<<dim3(512 / 64, 32), 256, 0, stream>>>(headbf, projwbf, projb, nullptr, bfeatbf,
                                                  2048, 512, 2048, 0);
  // q / k / v
  gemm_bt<<<dim3(1024 / 64, 32), 256, 0, stream>>>(statesbf, qkvwbf, qkvbias, nullptr, qkvbf,
                                                   2048, 1024, 1024, 0);
  // global-context summaries
  summary_kernel<<<32, 256, 0, stream>>>(states, summary);
  gkgv_kernel<<<32, 256, 0, stream>>>(summary, kw, kb, vw, vb, gkbuf, gvbuf);
  mix_kernel<<<512, 256, 0, stream>>>(states, mixw, mixb, mix);

  // attention
  local_attn_kernel<<<dim3(1024, 2), 256, 0, stream>>>(qkvbf, lctx);
  global_attn_kernel<<<dim3(256, 2), 256, 0, stream>>>(qkvbf, gkbuf, gvbuf, gctx);

  // fused partial feature:  base_feat + mix0*ls*lctx + mix1*gs*gctx
  fused_feat_kernel<<<4096, 256, 0, stream>>>(bfeatbf, lctx, gctx, mix, lsp, gsp, fusedbf);

  // big tied-embedding logits straight into d_out
  gemm_bt<<<dim3(32000 / 64, 32), 256, 0, stream>>>(bfeatbf, embbf, outbia, out, nullptr,
                                                    2048, 32000, 512, 0);
  // total_partial = fused_feat @ part_w^T + part_b
  gemm_bt<<<dim3(4096 / 64, 32), 256, 0, stream>>>(fusedbf, partwbf, partb, tpart, nullptr,
                                                   2048, 4096, 512, 0);
  // scatter into untied columns
  scatter_add_kernel<<<32768, 256, 0, stream>>>(tpart, untied, out);
}

// Round 3
// 5423.998 us; speedup vs baseline: 1.6432x; 1.6432x over previous
//
#include <hip/hip_runtime.h>

typedef short short8 __attribute__((ext_vector_type(8)));
typedef float f32x4  __attribute__((ext_vector_type(4)));

#define SCOPE_AGENT __HIP_MEMORY_SCOPE_AGENT

__device__ __forceinline__ ushort f2bf(float f){
  unsigned u = __float_as_uint(f);
  u = (u + 0x7FFFu + ((u >> 16) & 1u)) >> 16;
  return (ushort)u;
}
__device__ __forceinline__ float bf2f(ushort h){
  return __uint_as_float(((unsigned)h) << 16);
}
__device__ __forceinline__ float wred_sum(float v){
  #pragma unroll
  for (int m = 1; m < 64; m <<= 1) v += __shfl_xor(v, m, 64);
  return v;
}
__device__ __forceinline__ float wred_max(float v){
  #pragma unroll
  for (int m = 1; m < 64; m <<= 1) v = fmaxf(v, __shfl_xor(v, m, 64));
  return v;
}

// ---------------------------------------------------------------------------
// Generic bf16 MFMA GEMM:  C[M,N] = A[M,K] * W[N,K]^T (+bias) (+act)
// M,N multiples of 64; K multiple of 32. 64x64 block tile, 4 waves (2x2 of 32x32).
// act: 0 = none, 1 = relu^2
// ---------------------------------------------------------------------------
__global__ __launch_bounds__(256) void gemm_bt(
    const ushort* __restrict__ A, const ushort* __restrict__ W,
    const float* __restrict__ bias,
    float* __restrict__ outF, ushort* __restrict__ outB,
    int M, int N, int K, int act)
{
  __shared__ __align__(16) ushort As[64][56];   // 112B row stride: 16B aligned, ~2-way banks
  __shared__ __align__(16) ushort Ws[64][56];
  const int bn = blockIdx.x * 64, bm = blockIdx.y * 64;
  const int tid = threadIdx.x, lane = tid & 63, wave = tid >> 6;
  const int wm = (wave >> 1) * 32, wn = (wave & 1) * 32;
  const int lr = tid >> 2, lc = (tid & 3) * 8;
  const int fr = lane & 15, kg = (lane >> 4) * 8;

  f32x4 acc00 = {0.f,0.f,0.f,0.f}, acc01 = {0.f,0.f,0.f,0.f};
  f32x4 acc10 = {0.f,0.f,0.f,0.f}, acc11 = {0.f,0.f,0.f,0.f};

  const size_t arow = (size_t)(bm + lr) * K;
  const size_t wrow = (size_t)(bn + lr) * K;

  for (int k0 = 0; k0 < K; k0 += 32){
    *(uint4*)&As[lr][lc] = *(const uint4*)&A[arow + k0 + lc];
    *(uint4*)&Ws[lr][lc] = *(const uint4*)&W[wrow + k0 + lc];
    __syncthreads();
    short8 a0 = *(const short8*)&As[wm + fr][kg];
    short8 a1 = *(const short8*)&As[wm + 16 + fr][kg];
    short8 b0 = *(const short8*)&Ws[wn + fr][kg];
    short8 b1 = *(const short8*)&Ws[wn + 16 + fr][kg];
    acc00 = __builtin_amdgcn_mfma_f32_16x16x32_bf16(a0, b0, acc00, 0, 0, 0);
    acc01 = __builtin_amdgcn_mfma_f32_16x16x32_bf16(a0, b1, acc01, 0, 0, 0);
    acc10 = __builtin_amdgcn_mfma_f32_16x16x32_bf16(a1, b0, acc10, 0, 0, 0);
    acc11 = __builtin_amdgcn_mfma_f32_16x16x32_bf16(a1, b1, acc11, 0, 0, 0);
    __syncthreads();
  }

  const int rbase = bm + wm + (lane >> 4) * 4;
  #pragma unroll
  for (int fm = 0; fm < 2; ++fm){
    f32x4 v0 = fm ? acc10 : acc00;
    f32x4 v1 = fm ? acc11 : acc01;
    #pragma unroll
    for (int j = 0; j < 4; ++j){
      const int row = rbase + fm * 16 + j;
      {
        const int col = bn + wn + fr;
        float v = v0[j] + (bias ? bias[col] : 0.f);
        if (act == 1){ v = fmaxf(v, 0.f); v = v * v; }
        if (outF) outF[(size_t)row * N + col] = v;
        if (outB) outB[(size_t)row * N + col] = f2bf(v);
      }
      {
        const int col = bn + wn + 16 + fr;
        float v = v1[j] + (bias ? bias[col] : 0.f);
        if (act == 1){ v = fmaxf(v, 0.f); v = v * v; }
        if (outF) outF[(size_t)row * N + col] = v;
        if (outB) outB[(size_t)row * N + col] = f2bf(v);
      }
    }
  }
}

// ---------------------------------------------------------------------------
// Persistent dataflow GRU v2. 128 blocks x 256 threads (proven co-resident).
// Block owns hidden units U0..U0+7 for BOTH batches (weights shared across
// batch). Wave w computes units {U0+2w, U0+2w+1}. Wave 0 polls batch-0's
// 1024 h-words of step t-1 into LDS, wave 1 polls batch-1's; one
// __syncthreads; all 4 waves compute 12 dot products from LDS.
// Hand-off: write-once 0xFFFFFFFF sentinel words in hcomm (h in (-1,1) so
// the -NaN pattern is impossible), relaxed agent-scope atomics.
// hcomm layout: [t][b][1024] u32.  states: [b][t][1024] f32.
// ---------------------------------------------------------------------------
__global__ __launch_bounds__(256, 1) void gru_kernel(
    const float* __restrict__ xp,   // [b][t][3072] (includes b_ih)
    const float* __restrict__ whh,  // [3072][1024]
    const float* __restrict__ bhh,  // [3072]
    float* __restrict__ states,     // [b][t][1024]
    unsigned* __restrict__ hcomm)   // [1024][2][1024]
{
  const int wave = threadIdx.x >> 6, lane = threadIdx.x & 63;
  const int U0 = blockIdx.x * 8 + wave * 2;

  __shared__ float hbuf[2][2][1024];   // [buf][batch][unit]

  // weights: wrf[u][g][i] = whh[g*1024+U0+u][lane + 64*i]  (coalesced loads)
  float wrf[2][3][16];
  float bh[2][3];
  #pragma unroll
  for (int u = 0; u < 2; ++u){
    #pragma unroll
    for (int g = 0; g < 3; ++g){
      const int row = g * 1024 + U0 + u;
      const float* src = whh + (size_t)row * 1024 + lane;
      #pragma unroll
      for (int i = 0; i < 16; ++i) wrf[u][g][i] = src[i * 64];
      bh[u][g] = bhh[row];
    }
  }

  for (int t = 0; t < 1024; ++t){
    const int cur = t & 1;

    // xp prefetch for this step (independent of h); lanes 0..3: b=lane&1, u=lane>>1
    float xr = 0.f, xz = 0.f, xn = 0.f;
    if (lane < 4){
      const int b = lane & 1, u = lane >> 1;
      const size_t xoff = ((size_t)(b * 1024 + t)) * 3072 + (U0 + u);
      xr = xp[xoff]; xz = xp[xoff + 1024]; xn = xp[xoff + 2048];
    }

    // gather h_{t-1} into LDS: wave 0 -> batch 0, wave 1 -> batch 1
    if (wave < 2){
      const int b = wave;
      float* dst = &hbuf[cur][b][0];
      if (t == 0){
        #pragma unroll
        for (int i = 0; i < 16; ++i) dst[lane + 64 * i] = 0.f;   // h0 = 0
      } else {
        unsigned* hb = hcomm + (size_t)(t - 1) * 2048 + b * 1024;
        unsigned hu[16];
        #pragma unroll
        for (int i = 0; i < 16; ++i)
          hu[i] = __hip_atomic_load(hb + lane + 64 * i, __ATOMIC_RELAXED, SCOPE_AGENT);
        int guard = 0;
        while (1){
          int pend = 0;
          #pragma unroll
          for (int i = 0; i < 16; ++i) pend |= (hu[i] == 0xFFFFFFFFu) ? 1 : 0;
          if (!__any(pend)) break;
          if (++guard > (1 << 16)){
            // fail-safe: never hang; sanitize to finite wrong answer, not NaN
            #pragma unroll
            for (int i = 0; i < 16; ++i) if (hu[i] == 0xFFFFFFFFu) hu[i] = 0u;
            break;
          }
          __builtin_amdgcn_s_sleep(1);
          #pragma unroll
          for (int i = 0; i < 16; ++i){
            if (hu[i] == 0xFFFFFFFFu)
              hu[i] = __hip_atomic_load(hb + lane + 64 * i, __ATOMIC_RELAXED, SCOPE_AGENT);
          }
        }
        #pragma unroll
        for (int i = 0; i < 16; ++i) dst[lane + 64 * i] = __uint_as_float(hu[i]);
      }
    }
    __syncthreads();

    // 12 dot products: p[b][u][g] = sum_k h[b][k] * whh[g*1024+U0+u][k]
    float p[2][2][3];
    #pragma unroll
    for (int b = 0; b < 2; ++b)
      #pragma unroll
      for (int u = 0; u < 2; ++u)
        #pragma unroll
        for (int g = 0; g < 3; ++g) p[b][u][g] = 0.f;

    #pragma unroll
    for (int i = 0; i < 16; ++i){
      const float h0 = hbuf[cur][0][lane + 64 * i];
      const float h1 = hbuf[cur][1][lane + 64 * i];
      #pragma unroll
      for (int u = 0; u < 2; ++u)
        #pragma unroll
        for (int g = 0; g < 3; ++g){
          const float wv = wrf[u][g][i];
          p[0][u][g] = fmaf(h0, wv, p[0][u][g]);
          p[1][u][g] = fmaf(h1, wv, p[1][u][g]);
        }
    }
    #pragma unroll
    for (int b = 0; b < 2; ++b)
      #pragma unroll
      for (int u = 0; u < 2; ++u)
        #pragma unroll
        for (int g = 0; g < 3; ++g) p[b][u][g] = wred_sum(p[b][u][g]);

    if (lane < 4){
      const int b = lane & 1, u = lane >> 1, U = U0 + u;
      // static selection (all lanes hold all 12 sums after wred_sum)
      const float dr = (lane == 0) ? p[0][0][0] + bh[0][0]
                     : (lane == 1) ? p[1][0][0] + bh[0][0]
                     : (lane == 2) ? p[0][1][0] + bh[1][0]
                     :               p[1][1][0] + bh[1][0];
      const float dz = (lane == 0) ? p[0][0][1] + bh[0][1]
                     : (lane == 1) ? p[1][0][1] + bh[0][1]
                     : (lane == 2) ? p[0][1][1] + bh[1][1]
                     :               p[1][1][1] + bh[1][1];
      const float dn = (lane == 0) ? p[0][0][2] + bh[0][2]
                     : (lane == 1) ? p[1][0][2] + bh[0][2]
                     : (lane == 2) ? p[0][1][2] + bh[1][2]
                     :               p[1][1][2] + bh[1][2];
      const float rg = 1.f / (1.f + __expf(-(xr + dr)));
      const float zg = 1.f / (1.f + __expf(-(xz + dz)));
      const float ng = tanhf(xn + rg * dn);
      const float hp = hbuf[cur][b][U];          // h_{t-1} already staged in LDS
      const float hnew = (1.f - zg) * ng + zg * hp;
      states[((size_t)(b * 1024 + t)) * 1024 + U] = hnew;
      __hip_atomic_store(hcomm + (size_t)t * 2048 + b * 1024 + U, __float_as_uint(hnew),
                         __ATOMIC_RELAXED, SCOPE_AGENT);
    }
  }
}

// ---------------------------------------------------------------------------
// Small helper kernels
// ---------------------------------------------------------------------------
__global__ void fill_u32(unsigned* __restrict__ p, unsigned v, int n){
  int i = blockIdx.x * 256 + threadIdx.x;
  if (i < n) p[i] = v;
}

__global__ void f32_to_bf16(const float* __restrict__ s, ushort* __restrict__ d, int n){
  int i = blockIdx.x * 256 + threadIdx.x;
  if (i < n) d[i] = f2bf(s[i]);
}

__global__ void pack_qkvb_kernel(const float* qb, const float* kb, const float* vb, float* dst){
  int i = blockIdx.x * 256 + threadIdx.x;
  if (i < 1024) dst[i] = (i < 256) ? qb[i] : (i < 512) ? kb[i - 256] : vb[i - 512];
}

__global__ void gather_x_kernel(const int* __restrict__ ids, const float* __restrict__ emb,
                                ushort* __restrict__ x){
  int idx = blockIdx.x * 256 + threadIdx.x;    // 2048*512
  int r = idx >> 9, e = idx & 511;
  x[idx] = f2bf(emb[(size_t)ids[r] * 512 + e]);
}

__global__ void summary_kernel(const float* __restrict__ states, float* __restrict__ summary){
  int b = blockIdx.x >> 4, c = blockIdx.x & 15;
  for (int h = threadIdx.x; h < 1024; h += 256){
    float acc = 0.f;
    for (int t = 0; t < 64; ++t)
      acc += states[(size_t)(b * 1024 + c * 64 + t) * 1024 + h];
    summary[(size_t)(b * 16 + c) * 1024 + h] = acc * (1.f / 64.f);
  }
}

__global__ __launch_bounds__(256) void gkgv_kernel(
    const float* __restrict__ summary, const float* __restrict__ kw, const float* __restrict__ kb,
    const float* __restrict__ vw, const float* __restrict__ vb,
    float* __restrict__ gk, float* __restrict__ gv)
{
  int b = blockIdx.x >> 4, c = blockIdx.x & 15;
  __shared__ float s[1024];
  for (int i = threadIdx.x; i < 1024; i += 256)
    s[i] = summary[(size_t)(b * 16 + c) * 1024 + i];
  __syncthreads();
  for (int o = threadIdx.x; o < 768; o += 256){
    const float* w; float bias;
    if (o < 256){ w = kw + (size_t)o * 1024; bias = kb[o]; }
    else        { w = vw + (size_t)(o - 256) * 1024; bias = vb[o - 256]; }
    float acc = 0.f;
    for (int k = 0; k < 1024; ++k) acc = fmaf(s[k], w[k], acc);
    acc += bias;
    if (o < 256) gk[(size_t)(b * 16 + c) * 256 + o] = acc;
    else         gv[(size_t)(b * 16 + c) * 512 + (o - 256)] = acc;
  }
}

__global__ __launch_bounds__(256) void mix_kernel(
    const float* __restrict__ states, const float* __restrict__ mixw,
    const float* __restrict__ mixb, float* __restrict__ mix)
{
  int wave = threadIdx.x >> 6, lane = threadIdx.x & 63;
  int r = blockIdx.x * 4 + wave;
  const float* sr = states + (size_t)r * 1024;
  float d0 = 0.f, d1 = 0.f;
  #pragma unroll
  for (int i = 0; i < 16; ++i){
    float sv = sr[lane + 64 * i];
    d0 = fmaf(sv, mixw[lane + 64 * i], d0);
    d1 = fmaf(sv, mixw[1024 + lane + 64 * i], d1);
  }
  d0 = wred_sum(d0); d1 = wred_sum(d1);
  if (lane == 0){
    d0 += mixb[0]; d1 += mixb[1];
    float m = fmaxf(d0, d1);
    float e0 = __expf(d0 - m), e1 = __expf(d1 - m);
    float inv = 1.f / (e0 + e1);
    mix[r * 2] = e0 * inv; mix[r * 2 + 1] = e1 * inv;
  }
}

// qkv layout: [r][0..255]=q, [256..511]=k, [512..1023]=v (bf16)
__global__ __launch_bounds__(256) void local_attn_kernel(
    const ushort* __restrict__ qkv, ushort* __restrict__ lctx)
{
  const int qi = blockIdx.x, b = blockIdx.y;
  const int r = b * 1024 + qi;
  const int nk = min(qi, 128), ks0 = qi - nk;
  __shared__ float qf[256];
  __shared__ float sc[128];
  __shared__ float ps[128];
  const int tid = threadIdx.x;
  qf[tid] = bf2f(qkv[(size_t)r * 1024 + tid]);
  __syncthreads();
  if (tid < 128){
    float s = -1e30f;
    if (tid < nk){
      const ushort* krow = qkv + (size_t)(b * 1024 + ks0 + tid) * 1024 + 256;
      float acc = 0.f;
      for (int m = 0; m < 256; m += 2){
        unsigned u = *(const unsigned*)&krow[m];
        acc = fmaf(qf[m],     bf2f((ushort)(u & 0xFFFFu)), acc);
        acc = fmaf(qf[m + 1], bf2f((ushort)(u >> 16)),     acc);
      }
      s = acc * (1.f / 16.f);
    }
    sc[tid] = s;
  }
  __syncthreads();
  if (tid < 64){
    float s0 = sc[tid], s1 = sc[tid + 64];
    bool v0 = tid < nk, v1 = (tid + 64) < nk;
    float m = fmaxf(v0 ? s0 : -1e30f, v1 ? s1 : -1e30f);
    m = wred_max(m);
    float e0 = v0 ? __expf(s0 - m) : 0.f;
    float e1 = v1 ? __expf(s1 - m) : 0.f;
    float sum = wred_sum(e0 + e1);
    float inv = sum > 0.f ? 1.f / sum : 0.f;
    ps[tid] = e0 * inv; ps[tid + 64] = e1 * inv;
  }
  __syncthreads();
  float a0 = 0.f, a1 = 0.f;
  for (int j = 0; j < nk; ++j){
    float pj = ps[j];
    const ushort* vrow = qkv + (size_t)(b * 1024 + ks0 + j) * 1024 + 512;
    a0 = fmaf(pj, bf2f(vrow[tid]), a0);
    a1 = fmaf(pj, bf2f(vrow[tid + 256]), a1);
  }
  lctx[(size_t)r * 512 + tid] = f2bf(a0);
  lctx[(size_t)r * 512 + tid + 256] = f2bf(a1);
}

__global__ __launch_bounds__(256) void global_attn_kernel(
    const ushort* __restrict__ qkv, const float* __restrict__ gk,
    const float* __restrict__ gv, ushort* __restrict__ gctx)
{
  const int wave = threadIdx.x >> 6, lane = threadIdx.x & 63;
  const int qi = blockIdx.x * 4 + wave, b = blockIdx.y;
  const int r = b * 1024 + qi;
  float q4[4];
  {
    const ushort* qp = qkv + (size_t)r * 1024 + lane * 4;
    unsigned u0 = *(const unsigned*)&qp[0];
    unsigned u1 = *(const unsigned*)&qp[2];
    q4[0] = bf2f((ushort)(u0 & 0xFFFFu)); q4[1] = bf2f((ushort)(u0 >> 16));
    q4[2] = bf2f((ushort)(u1 & 0xFFFFu)); q4[3] = bf2f((ushort)(u1 >> 16));
  }
  float p[16];
  float mx = -1e30f;
  #pragma unroll
  for (int c = 0; c < 16; ++c){
    const float* gkr = gk + ((size_t)(b * 16 + c)) * 256 + lane * 4;
    float acc = q4[0]*gkr[0] + q4[1]*gkr[1] + q4[2]*gkr[2] + q4[3]*gkr[3];
    acc = wred_sum(acc);
    const bool valid = (c * 64 + 63) < (qi - 128);
    p[c] = valid ? acc * (1.f / 16.f) : -1e30f;
    if (valid) mx = fmaxf(mx, p[c]);
  }
  float sum = 0.f;
  #pragma unroll
  for (int c = 0; c < 16; ++c){
    const bool valid = (c * 64 + 63) < (qi - 128);
    float e = valid ? __expf(p[c] - mx) : 0.f;
    p[c] = e; sum += e;
  }
  const float inv = sum > 0.f ? 1.f / sum : 0.f;
  #pragma unroll
  for (int c = 0; c < 16; ++c) p[c] *= inv;
  #pragma unroll
  for (int i = 0; i < 8; ++i){
    float acc = 0.f;
    #pragma unroll
    for (int c = 0; c < 16; ++c)
      acc = fmaf(p[c], gv[((size_t)(b * 16 + c)) * 512 + i * 64 + lane], acc);
    gctx[(size_t)r * 512 + i * 64 + lane] = f2bf(acc);
  }
}

__global__ void fused_feat_kernel(
    const ushort* __restrict__ bfeat, const ushort* __restrict__ lc,
    const ushort* __restrict__ gc, const float* __restrict__ mix,
    const float* __restrict__ lsp, const float* __restrict__ gsp,
    ushort* __restrict__ outp)
{
  int idx = blockIdx.x * 256 + threadIdx.x;   // 2048*512
  int r = idx >> 9;
  float v = bf2f(bfeat[idx])
          + mix[r * 2]     * lsp[0] * bf2f(lc[idx])
          + mix[r * 2 + 1] * gsp[0] * bf2f(gc[idx]);
  outp[idx] = f2bf(v);
}

__global__ void scatter_add_kernel(const float* __restrict__ tp, const int* __restrict__ ids,
                                   float* __restrict__ out){
  int idx = blockIdx.x * 256 + threadIdx.x;   // 2048*4096
  int r = idx >> 12, pcol = idx & 4095;
  atomicAdd(&out[(size_t)r * 32000 + ids[pcol]], tp[idx]);
}

// ---------------------------------------------------------------------------
extern "C" void kernel_launch(void* const* d_in, const int* in_sizes, int n_in,
                              void* d_out, int out_size, void* d_ws, size_t ws_size,
                              hipStream_t stream)
{
  const int*   ids    = (const int*)  d_in[0];
  const int*   untied = (const int*)  d_in[1];
  const float* emb    = (const float*)d_in[2];
  const float* gwih   = (const float*)d_in[3];
  const float* gwhh   = (const float*)d_in[4];
  const float* gbih   = (const float*)d_in[5];
  const float* gbhh   = (const float*)d_in[6];
  const float* fcw    = (const float*)d_in[7];
  const float* fcb    = (const float*)d_in[8];
  const float* projw  = (const float*)d_in[9];
  const float* projb  = (const float*)d_in[10];
  const float* outbia = (const float*)d_in[11];
  const float* partw  = (const float*)d_in[12];
  const float* partb  = (const float*)d_in[13];
  const float* qw     = (const float*)d_in[14];
  const float* qb     = (const float*)d_in[15];
  const float* kw     = (const float*)d_in[16];
  const float* kb     = (const float*)d_in[17];
  const float* vw     = (const float*)d_in[18];
  const float* vb     = (const float*)d_in[19];
  const float* mixw   = (const float*)d_in[20];
  const float* mixb   = (const float*)d_in[21];
  const float* lsp    = (const float*)d_in[22];
  const float* gsp    = (const float*)d_in[23];
  float* out = (float*)d_out;

  char* base = (char*)d_ws;
  size_t off = 0;
  auto alloc = [&](size_t b)->char*{
    char* p = base + off; off += (b + 255) & ~(size_t)255; return p;
  };

  float*    regionA  = (float*)   alloc(2048ull * 4096 * 4);  // xp, then total_partial
  float*    xp       = regionA;                               // [2048][3072]
  float*    tpart    = regionA;                               // [2048][4096]
  float*    states   = (float*)   alloc(2048ull * 1024 * 4);
  ushort*   statesbf = (ushort*)  alloc(2048ull * 1024 * 2);
  ushort*   embbf    = (ushort*)  alloc(32000ull * 512 * 2);
  ushort*   xbf      = (ushort*)  alloc(2048ull * 512 * 2);
  ushort*   wihbf    = (ushort*)  alloc(3072ull * 512 * 2);
  ushort*   fcwbf    = (ushort*)  alloc(2048ull * 1024 * 2);
  ushort*   projwbf  = (ushort*)  alloc(512ull * 2048 * 2);
  ushort*   partwbf  = (ushort*)  alloc(4096ull * 512 * 2);
  ushort*   qkvwbf   = (ushort*)  alloc(1024ull * 1024 * 2);
  float*    qkvbias  = (float*)   alloc(1024 * 4);
  unsigned* hcomm    = (unsigned*)alloc(1024ull * 2048 * 4);  // then head_bf
  ushort*   headbf   = (ushort*)  hcomm;                      // [2048][2048]
  ushort*   bfeatbf  = (ushort*)  alloc(2048ull * 512 * 2);
  ushort*   qkvbf    = (ushort*)  alloc(2048ull * 1024 * 2);
  float*    summary  = (float*)   alloc(2ull * 16 * 1024 * 4);
  float*    gkbuf    = (float*)   alloc(2ull * 16 * 256 * 4);
  float*    gvbuf    = (float*)   alloc(2ull * 16 * 512 * 4);
  float*    mix      = (float*)   alloc(2048ull * 2 * 4);
  ushort*   lctx     = (ushort*)  alloc(2048ull * 512 * 2);
  ushort*   gctx     = (ushort*)  alloc(2048ull * 512 * 2);
  ushort*   fusedbf  = (ushort*)  alloc(2048ull * 512 * 2);
  if (off > ws_size) return;   // workspace too small: fail loudly (absmax) not OOB

  auto cv = [&](const float* s, ushort* d, long long n){
    f32_to_bf16<<<dim3((unsigned)((n + 255) / 256)), dim3(256), 0, stream>>>(s, d, (int)n);
  };

  // weight conversion / packing
  cv(emb,   embbf,   32000ll * 512);
  cv(gwih,  wihbf,   3072ll * 512);
  cv(fcw,   fcwbf,   2048ll * 1024);
  cv(projw, projwbf, 512ll * 2048);
  cv(partw, partwbf, 4096ll * 512);
  cv(qw, qkvwbf,               256ll * 1024);
  cv(kw, qkvwbf + 256 * 1024,  256ll * 1024);
  cv(vw, qkvwbf + 512 * 1024,  512ll * 1024);
  pack_qkvb_kernel<<<4, 256, 0, stream>>>(qb, kb, vb, qkvbias);
  fill_u32<<<(1024 * 2048 + 255) / 256, 256, 0, stream>>>(hcomm, 0xFFFFFFFFu, 1024 * 2048);

  // embedding gather + GRU input projection
  gather_x_kernel<<<4096, 256, 0, stream>>>(ids, emb, xbf);
  gemm_bt<<<dim3(3072 / 64, 32), 256, 0, stream>>>(xbf, wihbf, gbih, xp, nullptr,
                                                   2048, 3072, 512, 0);
  // recurrent core
  gru_kernel<<<128, 256, 0, stream>>>(xp, gwhh, gbhh, states, hcomm);
  cv(states, statesbf, 2048ll * 1024);

  // feed-forward head
  gemm_bt<<<dim3(2048 / 64, 32), 256, 0, stream>>>(statesbf, fcwbf, fcb, nullptr, headbf,
                                                   2048, 2048, 1024, 1);
  gemm_bt<<<dim3(512 / 64, 32), 256, 0, stream>>>(headbf, projwbf, projb, nullptr, bfeatbf,
                                                  2048, 512, 2048, 0);
  // q / k / v
  gemm_bt<<<dim3(1024 / 64, 32), 256, 0, stream>>>(statesbf, qkvwbf, qkvbias, nullptr, qkvbf,
                                                   2048, 1024, 1024, 0);
  // global-context summaries
  summary_kernel<<<32, 256, 0, stream>>>(states, summary);
  gkgv_kernel<<<32, 256, 0, stream>>>(summary, kw, kb, vw, vb, gkbuf, gvbuf);
  mix_kernel<<<512, 256, 0, stream>>>(states, mixw, mixb, mix);

  // attention
  local_attn_kernel<<<dim3(1024, 2), 256, 0, stream>>>(qkvbf, lctx);
  global_attn_kernel<<<dim3(256, 2), 256, 0, stream>>>(qkvbf, gkbuf, gvbuf, gctx);

  // fused partial feature:  base_feat + mix0*ls*lctx + mix1*gs*gctx
  fused_feat_kernel<<<4096, 256, 0, stream>>>(bfeatbf, lctx, gctx, mix, lsp, gsp, fusedbf);

  // big tied-embedding logits straight into d_out
  gemm_bt<<<dim3(32000 / 64, 32), 256, 0, stream>>>(bfeatbf, embbf, outbia, out, nullptr,
                                                    2048, 32000, 512, 0);
  // total_partial = fused_feat @ part_w^T + part_b
  gemm_bt<<<dim3(4096 / 64, 32), 256, 0, stream>>>(fusedbf, partwbf, partb, tpart, nullptr,
                                                   2048, 4096, 512, 0);
  // scatter into untied columns
  scatter_add_kernel<<<32768, 256, 0, stream>>>(tpart, untied, out);
}